// Round 1
// baseline (530.227 us; speedup 1.0000x reference)
//
#include <hip/hip_runtime.h>

// BoxCrossCategoryLoss: streaming row-wise loss over 6 x (N,2) f32 arrays.
// int index inputs are unused by the reference (recipes are constants).

__device__ __forceinline__ float relu_(float x) { return fmaxf(x, 0.0f); }

// Per-row loss. Inputs: vol_AB=(a0,a1), vol_BA=(b0,b1), vol_BC=(c0,c1),
// vol_CB=(d0,d1), vol_AC=(e0,e1), vol_CA=(f0,f1). All strictly negative.
__device__ __forceinline__ float row_loss(
    float a0, float a1, float b0, float b1,
    float c0, float c1, float d0, float d1,
    float e0, float e1, float f0, float f1)
{
    // w = 1 - exp(x) computed accurately via expm1; l = log1mexp(x) = log(w).
    float wa0 = -expm1f(a0), wb0 = -expm1f(b0);
    float wc0 = -expm1f(c0), wd0 = -expm1f(d0);
    float we0 = -expm1f(e0), wf0 = -expm1f(f0);
    float wa1 = -expm1f(a1), wb1 = -expm1f(b1);
    float wc1 = -expm1f(c1), wd1 = -expm1f(d1);
    float we1 = -expm1f(e1), wf1 = -expm1f(f1);

    float la0 = __logf(wa0), lb0 = __logf(wb0);
    float lc0 = __logf(wc0), ld0 = __logf(wd0);
    float la1 = __logf(wa1), lb1 = __logf(wb1);
    float lc1 = __logf(wc1), ld1 = __logf(wd1);
    float le1 = __logf(we1), lf1 = __logf(wf1);
    // le0, lf0 are only needed inside LACk -> use product form instead.

    // u = exp(x) reconstructed exactly from w.
    float ue0 = 1.0f - we0, uf0 = 1.0f - wf0;

    // LACk = log1mexp(pAC[k][:,0]):
    //   pAC[0][0] = e0 + lf0 = log(ue0*wf0) -> log(1 - ue0*wf0)
    //   pAC[1][0] = le0 + f0 = log(we0*uf0) -> log(1 - we0*uf0)
    //   pAC[2][0] = e0 + f0  = log(ue0*uf0) -> log(1 - ue0*uf0)
    float LAC0 = __logf(1.0f - ue0 * wf0);
    float LAC1 = __logf(1.0f - we0 * uf0);
    float LAC2 = __logf(1.0f - ue0 * uf0);

    // p[k] = [v1+l2, l1+v2, v1+v2, l1+l2]
    float AB00 = a0 + lb0, AB10 = la0 + b0, AB20 = a0 + b0;
    float AB01 = a1 + lb1, AB11 = la1 + b1, AB21 = a1 + b1, AB31 = la1 + lb1;
    float BC00 = c0 + ld0, BC10 = lc0 + d0, BC20 = c0 + d0;
    float BC01 = c1 + ld1, BC11 = lc1 + d1, BC21 = c1 + d1, BC31 = lc1 + ld1;
    float AC01 = e1 + lf1, AC11 = le1 + f1, AC21 = e1 + f1, AC31 = le1 + lf1;

    // 14 unique AB+BC sums shared across the 36 terms.
    float s1  = AB00 + BC01, s2  = AB00 + BC21, s3  = AB10 + BC11, s4  = AB10 + BC21;
    float s5  = AB20 + BC01, s6  = AB20 + BC11, s7  = AB20 + BC21, s8  = AB20 + BC31;
    float s9  = AB01 + BC00, s10 = AB01 + BC20, s11 = AB11 + BC10, s12 = AB11 + BC20;
    float s13 = AB21 + BC20, s14 = AB31 + BC20;

    float acc = 0.0f;
    // LOSS_RECIPE (14 terms)
    acc += relu_(s1 - AC01) + relu_(s2 - AC01) + relu_(s3 - AC11) + relu_(s4 - AC11);
    acc += relu_(s5 - AC01) + relu_(s6 - AC11) + relu_(s7 - AC21) + relu_(s8 - AC31);
    acc += relu_(s9 - AC01) + relu_(s10 - AC01) + relu_(s11 - AC11) + relu_(s12 - AC11);
    acc += relu_(s13 - AC21) + relu_(s14 - AC31);
    // NEG_LOSS_RECIPE (22 terms)
    acc += relu_(s1 - LAC1) + relu_(s1 - LAC2) + relu_(s2 - LAC1) + relu_(s2 - LAC2);
    acc += relu_(s3 - LAC0) + relu_(s3 - LAC2) + relu_(s4 - LAC0) + relu_(s4 - LAC2);
    acc += relu_(s5 - LAC1) + relu_(s5 - LAC2) + relu_(s6 - LAC0) + relu_(s6 - LAC2);
    acc += relu_(s9 - LAC1) + relu_(s9 - LAC2) + relu_(s10 - LAC1) + relu_(s10 - LAC2);
    acc += relu_(s11 - LAC0) + relu_(s11 - LAC2) + relu_(s12 - LAC0) + relu_(s12 - LAC2);
    acc += relu_(s8 - LAC2) + relu_(s14 - LAC2);
    return acc;
}

__global__ __launch_bounds__(256) void box_loss_kernel(
    const float* __restrict__ AB, const float* __restrict__ BA,
    const float* __restrict__ BC, const float* __restrict__ CB,
    const float* __restrict__ AC, const float* __restrict__ CA,
    float* __restrict__ out, int nElems)
{
    const int tid = blockIdx.x * blockDim.x + threadIdx.x;
    const long base = (long)tid * 4;  // 2 rows x 2 cols per thread
    float acc = 0.0f;

    if (base + 4 <= (long)nElems) {
        float4 ab = *(const float4*)(AB + base);
        float4 ba = *(const float4*)(BA + base);
        float4 bc = *(const float4*)(BC + base);
        float4 cb = *(const float4*)(CB + base);
        float4 ac = *(const float4*)(AC + base);
        float4 ca = *(const float4*)(CA + base);
        acc  = row_loss(ab.x, ab.y, ba.x, ba.y, bc.x, bc.y,
                        cb.x, cb.y, ac.x, ac.y, ca.x, ca.y);
        acc += row_loss(ab.z, ab.w, ba.z, ba.w, bc.z, bc.w,
                        cb.z, cb.w, ac.z, ac.w, ca.z, ca.w);
    } else if (base + 2 <= (long)nElems) {
        // tail: single row (only if N odd; N=8M is even, kept for safety)
        float2 ab = *(const float2*)(AB + base);
        float2 ba = *(const float2*)(BA + base);
        float2 bc = *(const float2*)(BC + base);
        float2 cb = *(const float2*)(CB + base);
        float2 ac = *(const float2*)(AC + base);
        float2 ca = *(const float2*)(CA + base);
        acc = row_loss(ab.x, ab.y, ba.x, ba.y, bc.x, bc.y,
                       cb.x, cb.y, ac.x, ac.y, ca.x, ca.y);
    }

    // wave64 butterfly reduce
    #pragma unroll
    for (int off = 32; off > 0; off >>= 1)
        acc += __shfl_down(acc, off, 64);

    __shared__ float wsum[4];
    const int lane = threadIdx.x & 63;
    const int wid  = threadIdx.x >> 6;
    if (lane == 0) wsum[wid] = acc;
    __syncthreads();
    if (threadIdx.x == 0) {
        float s = wsum[0] + wsum[1] + wsum[2] + wsum[3];
        atomicAdd(out, s);
    }
}

extern "C" void kernel_launch(void* const* d_in, const int* in_sizes, int n_in,
                              void* d_out, int out_size, void* d_ws, size_t ws_size,
                              hipStream_t stream) {
    const float* AB = (const float*)d_in[0];  // vol_AB
    const float* BA = (const float*)d_in[1];  // vol_BA
    const float* BC = (const float*)d_in[2];  // vol_BC
    const float* CB = (const float*)d_in[3];  // vol_CB
    const float* AC = (const float*)d_in[4];  // vol_AC
    const float* CA = (const float*)d_in[5];  // vol_CA
    // d_in[6..8] (xy/yz/xz rel ids) are unused by the reference.

    const int nElems = in_sizes[0];                 // N*2
    const int nThreads = (nElems + 3) / 4;          // 2 rows per thread
    const int block = 256;
    const int grid = (nThreads + block - 1) / block;

    // d_out is poisoned with 0xAA before every timed launch — zero it.
    hipMemsetAsync(d_out, 0, (size_t)out_size * sizeof(float), stream);
    box_loss_kernel<<<grid, block, 0, stream>>>(AB, BA, BC, CB, AC, CA,
                                                (float*)d_out, nElems);
}

// Round 2
// 456.231 us; speedup vs baseline: 1.1622x; 1.1622x over previous
//
#include <hip/hip_runtime.h>

// BoxCrossCategoryLoss: streaming row-wise loss over 6 x (N,2) f32 arrays.
// int index inputs are unused by the reference (recipes are constants).
//
// R2: replaced OCML expm1f/__logf library calls with raw hardware
// v_exp_f32 / v_log_f32 (base-2), computing all sums in log2 units and
// scaling the per-thread total by ln(2) once. Threshold is 2% relative;
// the 1-exp cancellation error (~eps/w per log) is orders below it.

#define LOG2E 1.4426950408889634f
#define LN2   0.6931471805599453f

__device__ __forceinline__ float fexp2(float x) { return __builtin_amdgcn_exp2f(x); }
__device__ __forceinline__ float flog2(float x) { return __builtin_amdgcn_logf(x); }
__device__ __forceinline__ float relu_(float x) { return fmaxf(x, 0.0f); }

// Per-row loss in LOG2 UNITS. Raw natural-log inputs:
// vol_AB=(a0,a1), vol_BA=(b0,b1), vol_BC=(c0,c1), vol_CB=(d0,d1),
// vol_AC=(e0,e1), vol_CA=(f0,f1). All strictly negative.
__device__ __forceinline__ float row_loss_l2(
    float a0, float a1, float b0, float b1,
    float c0, float c1, float d0, float d1,
    float e0, float e1, float f0, float f1)
{
    // scaled inputs (log2 units) — also the exp2 arguments
    float a0s = a0 * LOG2E, a1s = a1 * LOG2E;
    float b0s = b0 * LOG2E, b1s = b1 * LOG2E;
    float c0s = c0 * LOG2E, c1s = c1 * LOG2E;
    float d0s = d0 * LOG2E, d1s = d1 * LOG2E;
    float e0s = e0 * LOG2E, e1s = e1 * LOG2E;
    float f0s = f0 * LOG2E, f1s = f1 * LOG2E;

    // u = exp(x) via hardware exp2; w = 1 - u
    float ua0 = fexp2(a0s), ub0 = fexp2(b0s), uc0 = fexp2(c0s), ud0 = fexp2(d0s);
    float ue0 = fexp2(e0s), uf0 = fexp2(f0s);
    float ua1 = fexp2(a1s), ub1 = fexp2(b1s), uc1 = fexp2(c1s), ud1 = fexp2(d1s);
    float ue1 = fexp2(e1s), uf1 = fexp2(f1s);

    float wa0 = 1.0f - ua0, wb0 = 1.0f - ub0, wc0 = 1.0f - uc0, wd0 = 1.0f - ud0;
    float we0 = 1.0f - ue0, wf0 = 1.0f - uf0;
    float wa1 = 1.0f - ua1, wb1 = 1.0f - ub1, wc1 = 1.0f - uc1, wd1 = 1.0f - ud1;
    float we1 = 1.0f - ue1, wf1 = 1.0f - uf1;

    // l = log2(1 - exp(x)) via hardware log2 (10 needed individually)
    float la0 = flog2(wa0), lb0 = flog2(wb0), lc0 = flog2(wc0), ld0 = flog2(wd0);
    float la1 = flog2(wa1), lb1 = flog2(wb1), lc1 = flog2(wc1), ld1 = flog2(wd1);
    float le1 = flog2(we1), lf1 = flog2(wf1);

    // LACk = log1mexp(pAC[k][:,0]) in log2 units:
    //   pAC[0][0]=log(ue0*wf0), pAC[1][0]=log(we0*uf0), pAC[2][0]=log(ue0*uf0)
    float LAC0 = flog2(fmaf(-ue0, wf0, 1.0f));
    float LAC1 = flog2(fmaf(-we0, uf0, 1.0f));
    float LAC2 = flog2(fmaf(-ue0, uf0, 1.0f));

    // p[k] = [v1+l2, l1+v2, v1+v2, l1+l2]  (log2 units)
    float AB00 = a0s + lb0, AB10 = la0 + b0s, AB20 = a0s + b0s;
    float AB01 = a1s + lb1, AB11 = la1 + b1s, AB21 = a1s + b1s, AB31 = la1 + lb1;
    float BC00 = c0s + ld0, BC10 = lc0 + d0s, BC20 = c0s + d0s;
    float BC01 = c1s + ld1, BC11 = lc1 + d1s, BC21 = c1s + d1s, BC31 = lc1 + ld1;
    float AC01 = e1s + lf1, AC11 = le1 + f1s, AC21 = e1s + f1s, AC31 = le1 + lf1;

    // 14 unique AB+BC sums shared across the 36 terms.
    float s1  = AB00 + BC01, s2  = AB00 + BC21, s3  = AB10 + BC11, s4  = AB10 + BC21;
    float s5  = AB20 + BC01, s6  = AB20 + BC11, s7  = AB20 + BC21, s8  = AB20 + BC31;
    float s9  = AB01 + BC00, s10 = AB01 + BC20, s11 = AB11 + BC10, s12 = AB11 + BC20;
    float s13 = AB21 + BC20, s14 = AB31 + BC20;

    float acc = 0.0f;
    // LOSS_RECIPE (14 terms)
    acc += relu_(s1 - AC01) + relu_(s2 - AC01) + relu_(s3 - AC11) + relu_(s4 - AC11);
    acc += relu_(s5 - AC01) + relu_(s6 - AC11) + relu_(s7 - AC21) + relu_(s8 - AC31);
    acc += relu_(s9 - AC01) + relu_(s10 - AC01) + relu_(s11 - AC11) + relu_(s12 - AC11);
    acc += relu_(s13 - AC21) + relu_(s14 - AC31);
    // NEG_LOSS_RECIPE (22 terms)
    acc += relu_(s1 - LAC1) + relu_(s1 - LAC2) + relu_(s2 - LAC1) + relu_(s2 - LAC2);
    acc += relu_(s3 - LAC0) + relu_(s3 - LAC2) + relu_(s4 - LAC0) + relu_(s4 - LAC2);
    acc += relu_(s5 - LAC1) + relu_(s5 - LAC2) + relu_(s6 - LAC0) + relu_(s6 - LAC2);
    acc += relu_(s9 - LAC1) + relu_(s9 - LAC2) + relu_(s10 - LAC1) + relu_(s10 - LAC2);
    acc += relu_(s11 - LAC0) + relu_(s11 - LAC2) + relu_(s12 - LAC0) + relu_(s12 - LAC2);
    acc += relu_(s8 - LAC2) + relu_(s14 - LAC2);
    return acc;  // log2 units
}

__global__ __launch_bounds__(256) void box_loss_kernel(
    const float* __restrict__ AB, const float* __restrict__ BA,
    const float* __restrict__ BC, const float* __restrict__ CB,
    const float* __restrict__ AC, const float* __restrict__ CA,
    float* __restrict__ out, int nElems)
{
    const int tid = blockIdx.x * blockDim.x + threadIdx.x;
    float acc = 0.0f;

    // 4 rows (8 elements) per thread: 2 float4 segments per array → ILP
    // across the v_exp/v_log dependency chains.
    #pragma unroll
    for (int k = 0; k < 2; ++k) {
        const long base = (long)tid * 8 + 4 * k;
        if (base + 4 <= (long)nElems) {
            float4 ab = *(const float4*)(AB + base);
            float4 ba = *(const float4*)(BA + base);
            float4 bc = *(const float4*)(BC + base);
            float4 cb = *(const float4*)(CB + base);
            float4 ac = *(const float4*)(AC + base);
            float4 ca = *(const float4*)(CA + base);
            acc += row_loss_l2(ab.x, ab.y, ba.x, ba.y, bc.x, bc.y,
                               cb.x, cb.y, ac.x, ac.y, ca.x, ca.y);
            acc += row_loss_l2(ab.z, ab.w, ba.z, ba.w, bc.z, bc.w,
                               cb.z, cb.w, ac.z, ac.w, ca.z, ca.w);
        } else if (base + 2 <= (long)nElems) {
            float2 ab = *(const float2*)(AB + base);
            float2 ba = *(const float2*)(BA + base);
            float2 bc = *(const float2*)(BC + base);
            float2 cb = *(const float2*)(CB + base);
            float2 ac = *(const float2*)(AC + base);
            float2 ca = *(const float2*)(CA + base);
            acc += row_loss_l2(ab.x, ab.y, ba.x, ba.y, bc.x, bc.y,
                               cb.x, cb.y, ac.x, ac.y, ca.x, ca.y);
        }
    }

    acc *= LN2;  // convert log2-unit total back to natural units

    // wave64 butterfly reduce
    #pragma unroll
    for (int off = 32; off > 0; off >>= 1)
        acc += __shfl_down(acc, off, 64);

    __shared__ float wsum[4];
    const int lane = threadIdx.x & 63;
    const int wid  = threadIdx.x >> 6;
    if (lane == 0) wsum[wid] = acc;
    __syncthreads();
    if (threadIdx.x == 0) {
        float s = wsum[0] + wsum[1] + wsum[2] + wsum[3];
        atomicAdd(out, s);
    }
}

extern "C" void kernel_launch(void* const* d_in, const int* in_sizes, int n_in,
                              void* d_out, int out_size, void* d_ws, size_t ws_size,
                              hipStream_t stream) {
    const float* AB = (const float*)d_in[0];  // vol_AB
    const float* BA = (const float*)d_in[1];  // vol_BA
    const float* BC = (const float*)d_in[2];  // vol_BC
    const float* CB = (const float*)d_in[3];  // vol_CB
    const float* AC = (const float*)d_in[4];  // vol_AC
    const float* CA = (const float*)d_in[5];  // vol_CA
    // d_in[6..8] (xy/yz/xz rel ids) are unused by the reference.

    const int nElems = in_sizes[0];                   // N*2
    const long nThreads = ((long)nElems + 7) / 8;     // 4 rows per thread
    const int block = 256;
    const int grid = (int)((nThreads + block - 1) / block);

    // d_out is poisoned with 0xAA before every timed launch — zero it.
    hipMemsetAsync(d_out, 0, (size_t)out_size * sizeof(float), stream);
    box_loss_kernel<<<grid, block, 0, stream>>>(AB, BA, BC, CB, AC, CA,
                                                (float*)d_out, nElems);
}

// Round 3
// 452.166 us; speedup vs baseline: 1.1726x; 1.0090x over previous
//
#include <hip/hip_runtime.h>

// BoxCrossCategoryLoss: streaming row-wise loss over 6 x (N,2) f32 arrays.
// int index inputs are unused by the reference (recipes are constants).
//
// R3: latency-bound fix. R2 had VGPR_Count=36 -> compiler serialized the 12
// float4 loads (1-2 KB in flight/wave vs the ~9 KB/CU Little's-law target).
// Now: straight-line body, all 12 loads issued before any compute, tail
// handled by address-clamp + zero-mask (no branches around loads),
// __launch_bounds__(256,4) to allow ~128 VGPRs.

#define LOG2E 1.4426950408889634f
#define LN2   0.6931471805599453f

__device__ __forceinline__ float fexp2(float x) { return __builtin_amdgcn_exp2f(x); }
__device__ __forceinline__ float flog2(float x) { return __builtin_amdgcn_logf(x); }
__device__ __forceinline__ float relu_(float x) { return fmaxf(x, 0.0f); }

// Per-row loss in LOG2 UNITS. Raw natural-log inputs (strictly negative).
__device__ __forceinline__ float row_loss_l2(
    float a0, float a1, float b0, float b1,
    float c0, float c1, float d0, float d1,
    float e0, float e1, float f0, float f1)
{
    // scaled inputs (log2 units) — also the exp2 arguments
    float a0s = a0 * LOG2E, a1s = a1 * LOG2E;
    float b0s = b0 * LOG2E, b1s = b1 * LOG2E;
    float c0s = c0 * LOG2E, c1s = c1 * LOG2E;
    float d0s = d0 * LOG2E, d1s = d1 * LOG2E;
    float e0s = e0 * LOG2E, e1s = e1 * LOG2E;
    float f0s = f0 * LOG2E, f1s = f1 * LOG2E;

    // u = exp(x) via hardware exp2; w = 1 - u
    float ua0 = fexp2(a0s), ub0 = fexp2(b0s), uc0 = fexp2(c0s), ud0 = fexp2(d0s);
    float ue0 = fexp2(e0s), uf0 = fexp2(f0s);
    float ua1 = fexp2(a1s), ub1 = fexp2(b1s), uc1 = fexp2(c1s), ud1 = fexp2(d1s);
    float ue1 = fexp2(e1s), uf1 = fexp2(f1s);

    float wa0 = 1.0f - ua0, wb0 = 1.0f - ub0, wc0 = 1.0f - uc0, wd0 = 1.0f - ud0;
    float we0 = 1.0f - ue0, wf0 = 1.0f - uf0;
    float wa1 = 1.0f - ua1, wb1 = 1.0f - ub1, wc1 = 1.0f - uc1, wd1 = 1.0f - ud1;
    float we1 = 1.0f - ue1, wf1 = 1.0f - uf1;

    // l = log2(1 - exp(x)) via hardware log2 (10 needed individually)
    float la0 = flog2(wa0), lb0 = flog2(wb0), lc0 = flog2(wc0), ld0 = flog2(wd0);
    float la1 = flog2(wa1), lb1 = flog2(wb1), lc1 = flog2(wc1), ld1 = flog2(wd1);
    float le1 = flog2(we1), lf1 = flog2(wf1);

    // LACk = log1mexp(pAC[k][:,0]) in log2 units:
    float LAC0 = flog2(fmaf(-ue0, wf0, 1.0f));
    float LAC1 = flog2(fmaf(-we0, uf0, 1.0f));
    float LAC2 = flog2(fmaf(-ue0, uf0, 1.0f));

    // p[k] = [v1+l2, l1+v2, v1+v2, l1+l2]  (log2 units)
    float AB00 = a0s + lb0, AB10 = la0 + b0s, AB20 = a0s + b0s;
    float AB01 = a1s + lb1, AB11 = la1 + b1s, AB21 = a1s + b1s, AB31 = la1 + lb1;
    float BC00 = c0s + ld0, BC10 = lc0 + d0s, BC20 = c0s + d0s;
    float BC01 = c1s + ld1, BC11 = lc1 + d1s, BC21 = c1s + d1s, BC31 = lc1 + ld1;
    float AC01 = e1s + lf1, AC11 = le1 + f1s, AC21 = e1s + f1s, AC31 = le1 + lf1;

    // 14 unique AB+BC sums shared across the 36 terms.
    float s1  = AB00 + BC01, s2  = AB00 + BC21, s3  = AB10 + BC11, s4  = AB10 + BC21;
    float s5  = AB20 + BC01, s6  = AB20 + BC11, s7  = AB20 + BC21, s8  = AB20 + BC31;
    float s9  = AB01 + BC00, s10 = AB01 + BC20, s11 = AB11 + BC10, s12 = AB11 + BC20;
    float s13 = AB21 + BC20, s14 = AB31 + BC20;

    // Two independent accumulator chains for add ILP.
    float p = 0.0f, q = 0.0f;
    // LOSS_RECIPE (14 terms)
    p += relu_(s1 - AC01) + relu_(s2 - AC01) + relu_(s3 - AC11) + relu_(s4 - AC11);
    q += relu_(s5 - AC01) + relu_(s6 - AC11) + relu_(s7 - AC21) + relu_(s8 - AC31);
    p += relu_(s9 - AC01) + relu_(s10 - AC01) + relu_(s11 - AC11) + relu_(s12 - AC11);
    q += relu_(s13 - AC21) + relu_(s14 - AC31);
    // NEG_LOSS_RECIPE (22 terms)
    p += relu_(s1 - LAC1) + relu_(s1 - LAC2) + relu_(s2 - LAC1) + relu_(s2 - LAC2);
    q += relu_(s3 - LAC0) + relu_(s3 - LAC2) + relu_(s4 - LAC0) + relu_(s4 - LAC2);
    p += relu_(s5 - LAC1) + relu_(s5 - LAC2) + relu_(s6 - LAC0) + relu_(s6 - LAC2);
    q += relu_(s9 - LAC1) + relu_(s9 - LAC2) + relu_(s10 - LAC1) + relu_(s10 - LAC2);
    p += relu_(s11 - LAC0) + relu_(s11 - LAC2) + relu_(s12 - LAC0) + relu_(s12 - LAC2);
    q += relu_(s8 - LAC2) + relu_(s14 - LAC2);
    return p + q;  // log2 units
}

__device__ __forceinline__ float pair_loss(float4 ab, float4 ba, float4 bc,
                                           float4 cb, float4 ac, float4 ca)
{
    return row_loss_l2(ab.x, ab.y, ba.x, ba.y, bc.x, bc.y,
                       cb.x, cb.y, ac.x, ac.y, ca.x, ca.y)
         + row_loss_l2(ab.z, ab.w, ba.z, ba.w, bc.z, bc.w,
                       cb.z, cb.w, ac.z, ac.w, ca.z, ca.w);
}

__global__ __launch_bounds__(256, 4) void box_loss_kernel(
    const float* __restrict__ AB, const float* __restrict__ BA,
    const float* __restrict__ BC, const float* __restrict__ CB,
    const float* __restrict__ AC, const float* __restrict__ CA,
    float* __restrict__ out, int nElems)
{
    // Block owns a contiguous 2048-element chunk (256 thr x 8 elems).
    // Thread t: segment0 at chunk+4t, segment1 at chunk+1024+4t.
    // Both are perfectly coalesced 1 KB/wave loads.
    const long chunk = (long)blockIdx.x * 2048;
    const int  t     = threadIdx.x;
    const long b0    = chunk + 4 * t;
    const long b1    = chunk + 1024 + 4 * t;
    const long nE    = (long)nElems;

    // Branch-free tail: clamp OOB addresses to 0 (valid data), zero the mask.
    const bool v0 = (b0 + 4) <= nE;
    const bool v1 = (b1 + 4) <= nE;
    const long a0 = v0 ? b0 : 0;
    const long a1 = v1 ? b1 : 0;
    const float m0 = v0 ? 1.0f : 0.0f;
    const float m1 = v1 ? 1.0f : 0.0f;

    // All 12 loads issued before any dependent compute -> 12 KB in flight/wave.
    float4 ab0 = *(const float4*)(AB + a0);
    float4 ba0 = *(const float4*)(BA + a0);
    float4 bc0 = *(const float4*)(BC + a0);
    float4 cb0 = *(const float4*)(CB + a0);
    float4 ac0 = *(const float4*)(AC + a0);
    float4 ca0 = *(const float4*)(CA + a0);
    float4 ab1 = *(const float4*)(AB + a1);
    float4 ba1 = *(const float4*)(BA + a1);
    float4 bc1 = *(const float4*)(BC + a1);
    float4 cb1 = *(const float4*)(CB + a1);
    float4 ac1 = *(const float4*)(AC + a1);
    float4 ca1 = *(const float4*)(CA + a1);

    float acc = m0 * pair_loss(ab0, ba0, bc0, cb0, ac0, ca0)
              + m1 * pair_loss(ab1, ba1, bc1, cb1, ac1, ca1);

    acc *= LN2;  // convert log2-unit total back to natural units

    // wave64 butterfly reduce
    #pragma unroll
    for (int off = 32; off > 0; off >>= 1)
        acc += __shfl_down(acc, off, 64);

    __shared__ float wsum[4];
    const int lane = threadIdx.x & 63;
    const int wid  = threadIdx.x >> 6;
    if (lane == 0) wsum[wid] = acc;
    __syncthreads();
    if (threadIdx.x == 0) {
        float s = wsum[0] + wsum[1] + wsum[2] + wsum[3];
        atomicAdd(out, s);
    }
}

extern "C" void kernel_launch(void* const* d_in, const int* in_sizes, int n_in,
                              void* d_out, int out_size, void* d_ws, size_t ws_size,
                              hipStream_t stream) {
    const float* AB = (const float*)d_in[0];  // vol_AB
    const float* BA = (const float*)d_in[1];  // vol_BA
    const float* BC = (const float*)d_in[2];  // vol_BC
    const float* CB = (const float*)d_in[3];  // vol_CB
    const float* AC = (const float*)d_in[4];  // vol_AC
    const float* CA = (const float*)d_in[5];  // vol_CA
    // d_in[6..8] (xy/yz/xz rel ids) are unused by the reference.

    const long nElems = in_sizes[0];                  // N*2
    const long nChunks = (nElems + 2047) / 2048;      // 2048 elems per block
    const int block = 256;
    const int grid = (int)nChunks;

    // d_out is poisoned with 0xAA before every timed launch — zero it.
    hipMemsetAsync(d_out, 0, (size_t)out_size * sizeof(float), stream);
    box_loss_kernel<<<grid, block, 0, stream>>>(AB, BA, BC, CB, AC, CA,
                                                (float*)d_out, (int)nElems);
}

// Round 4
// 439.676 us; speedup vs baseline: 1.2059x; 1.0284x over previous
//
#include <hip/hip_runtime.h>

// BoxCrossCategoryLoss: streaming row-wise loss over 6 x (N,2) f32 arrays.
// int index inputs are unused by the reference (recipes are constants).
//
// R4: software-pipelined grid-stride loop. R3 showed the compiler sinks
// loads to their consumers (VGPR=28 -> ~1-2 KB in flight/wave, load/compute
// serialized, 2.7 TB/s delivered, VALUBusy 32%). Now each iteration
// prefetches the NEXT 6-float4 segment, then a sched_barrier(0) pins the
// prefetch above the current segment's compute, so ~6 KB/wave stays in
// flight across the whole ~800-cycle compute phase.

#define LOG2E 1.4426950408889634f
#define LN2   0.6931471805599453f

__device__ __forceinline__ float fexp2(float x) { return __builtin_amdgcn_exp2f(x); }
__device__ __forceinline__ float flog2(float x) { return __builtin_amdgcn_logf(x); }
__device__ __forceinline__ float relu_(float x) { return fmaxf(x, 0.0f); }

// Per-row loss in LOG2 UNITS. Raw natural-log inputs (strictly negative).
__device__ __forceinline__ float row_loss_l2(
    float a0, float a1, float b0, float b1,
    float c0, float c1, float d0, float d1,
    float e0, float e1, float f0, float f1)
{
    // scaled inputs (log2 units) — also the exp2 arguments
    float a0s = a0 * LOG2E, a1s = a1 * LOG2E;
    float b0s = b0 * LOG2E, b1s = b1 * LOG2E;
    float c0s = c0 * LOG2E, c1s = c1 * LOG2E;
    float d0s = d0 * LOG2E, d1s = d1 * LOG2E;
    float e0s = e0 * LOG2E, e1s = e1 * LOG2E;
    float f0s = f0 * LOG2E, f1s = f1 * LOG2E;

    // u = exp(x) via hardware exp2; w = 1 - u
    float ua0 = fexp2(a0s), ub0 = fexp2(b0s), uc0 = fexp2(c0s), ud0 = fexp2(d0s);
    float ue0 = fexp2(e0s), uf0 = fexp2(f0s);
    float ua1 = fexp2(a1s), ub1 = fexp2(b1s), uc1 = fexp2(c1s), ud1 = fexp2(d1s);
    float ue1 = fexp2(e1s), uf1 = fexp2(f1s);

    float wa0 = 1.0f - ua0, wb0 = 1.0f - ub0, wc0 = 1.0f - uc0, wd0 = 1.0f - ud0;
    float we0 = 1.0f - ue0, wf0 = 1.0f - uf0;
    float wa1 = 1.0f - ua1, wb1 = 1.0f - ub1, wc1 = 1.0f - uc1, wd1 = 1.0f - ud1;
    float we1 = 1.0f - ue1, wf1 = 1.0f - uf1;

    // l = log2(1 - exp(x)) via hardware log2 (10 needed individually)
    float la0 = flog2(wa0), lb0 = flog2(wb0), lc0 = flog2(wc0), ld0 = flog2(wd0);
    float la1 = flog2(wa1), lb1 = flog2(wb1), lc1 = flog2(wc1), ld1 = flog2(wd1);
    float le1 = flog2(we1), lf1 = flog2(wf1);

    // LACk = log1mexp(pAC[k][:,0]) in log2 units:
    float LAC0 = flog2(fmaf(-ue0, wf0, 1.0f));
    float LAC1 = flog2(fmaf(-we0, uf0, 1.0f));
    float LAC2 = flog2(fmaf(-ue0, uf0, 1.0f));

    // p[k] = [v1+l2, l1+v2, v1+v2, l1+l2]  (log2 units)
    float AB00 = a0s + lb0, AB10 = la0 + b0s, AB20 = a0s + b0s;
    float AB01 = a1s + lb1, AB11 = la1 + b1s, AB21 = a1s + b1s, AB31 = la1 + lb1;
    float BC00 = c0s + ld0, BC10 = lc0 + d0s, BC20 = c0s + d0s;
    float BC01 = c1s + ld1, BC11 = lc1 + d1s, BC21 = c1s + d1s, BC31 = lc1 + ld1;
    float AC01 = e1s + lf1, AC11 = le1 + f1s, AC21 = e1s + f1s, AC31 = le1 + lf1;

    // 14 unique AB+BC sums shared across the 36 terms.
    float s1  = AB00 + BC01, s2  = AB00 + BC21, s3  = AB10 + BC11, s4  = AB10 + BC21;
    float s5  = AB20 + BC01, s6  = AB20 + BC11, s7  = AB20 + BC21, s8  = AB20 + BC31;
    float s9  = AB01 + BC00, s10 = AB01 + BC20, s11 = AB11 + BC10, s12 = AB11 + BC20;
    float s13 = AB21 + BC20, s14 = AB31 + BC20;

    // Two independent accumulator chains for add ILP.
    float p = 0.0f, q = 0.0f;
    // LOSS_RECIPE (14 terms)
    p += relu_(s1 - AC01) + relu_(s2 - AC01) + relu_(s3 - AC11) + relu_(s4 - AC11);
    q += relu_(s5 - AC01) + relu_(s6 - AC11) + relu_(s7 - AC21) + relu_(s8 - AC31);
    p += relu_(s9 - AC01) + relu_(s10 - AC01) + relu_(s11 - AC11) + relu_(s12 - AC11);
    q += relu_(s13 - AC21) + relu_(s14 - AC31);
    // NEG_LOSS_RECIPE (22 terms)
    p += relu_(s1 - LAC1) + relu_(s1 - LAC2) + relu_(s2 - LAC1) + relu_(s2 - LAC2);
    q += relu_(s3 - LAC0) + relu_(s3 - LAC2) + relu_(s4 - LAC0) + relu_(s4 - LAC2);
    p += relu_(s5 - LAC1) + relu_(s5 - LAC2) + relu_(s6 - LAC0) + relu_(s6 - LAC2);
    q += relu_(s9 - LAC1) + relu_(s9 - LAC2) + relu_(s10 - LAC1) + relu_(s10 - LAC2);
    p += relu_(s11 - LAC0) + relu_(s11 - LAC2) + relu_(s12 - LAC0) + relu_(s12 - LAC2);
    q += relu_(s8 - LAC2) + relu_(s14 - LAC2);
    return p + q;  // log2 units
}

struct Seg {
    float4 ab, ba, bc, cb, ac, ca;
};

__device__ __forceinline__ float pair_loss(const Seg& s)
{
    return row_loss_l2(s.ab.x, s.ab.y, s.ba.x, s.ba.y, s.bc.x, s.bc.y,
                       s.cb.x, s.cb.y, s.ac.x, s.ac.y, s.ca.x, s.ca.y)
         + row_loss_l2(s.ab.z, s.ab.w, s.ba.z, s.ba.w, s.bc.z, s.bc.w,
                       s.cb.z, s.cb.w, s.ac.z, s.ac.w, s.ca.z, s.ca.w);
}

__global__ __launch_bounds__(256, 4) void box_loss_kernel(
    const float* __restrict__ AB, const float* __restrict__ BA,
    const float* __restrict__ BC, const float* __restrict__ CB,
    const float* __restrict__ AC, const float* __restrict__ CA,
    float* __restrict__ out, long nElems)
{
    const long nE = nElems;
    const long stride = (long)gridDim.x * blockDim.x * 4;
    long idx = ((long)blockIdx.x * blockDim.x + threadIdx.x) * 4;
    const int nIter = (int)((nE + stride - 1) / stride);

    // Branch-free bounds: clamp OOB address to 0 (valid data), zero the mask.
    #define LOAD_SEG(dst, msk, base)                        \
        do {                                                \
            bool v_ = ((base) + 4) <= nE;                   \
            long a_ = v_ ? (base) : 0;                      \
            (msk) = v_ ? 1.0f : 0.0f;                       \
            (dst).ab = *(const float4*)(AB + a_);           \
            (dst).ba = *(const float4*)(BA + a_);           \
            (dst).bc = *(const float4*)(BC + a_);           \
            (dst).cb = *(const float4*)(CB + a_);           \
            (dst).ac = *(const float4*)(AC + a_);           \
            (dst).ca = *(const float4*)(CA + a_);           \
        } while (0)

    float acc = 0.0f;
    Seg cur, nxt;
    float mcur, mnxt;
    LOAD_SEG(cur, mcur, idx);
    long p = idx + stride;

    for (int it = 1; it < nIter; ++it) {
        // Prefetch next segment...
        LOAD_SEG(nxt, mnxt, p);
        // ...and pin it ABOVE the current segment's compute so the 6 KB
        // stays in flight across the ~800-cycle compute phase.
        __builtin_amdgcn_sched_barrier(0);
        acc += mcur * pair_loss(cur);
        cur = nxt;
        mcur = mnxt;
        p += stride;
    }
    acc += mcur * pair_loss(cur);
    #undef LOAD_SEG

    acc *= LN2;  // convert log2-unit total back to natural units

    // wave64 butterfly reduce
    #pragma unroll
    for (int off = 32; off > 0; off >>= 1)
        acc += __shfl_down(acc, off, 64);

    __shared__ float wsum[4];
    const int lane = threadIdx.x & 63;
    const int wid  = threadIdx.x >> 6;
    if (lane == 0) wsum[wid] = acc;
    __syncthreads();
    if (threadIdx.x == 0) {
        float s = wsum[0] + wsum[1] + wsum[2] + wsum[3];
        atomicAdd(out, s);
    }
}

extern "C" void kernel_launch(void* const* d_in, const int* in_sizes, int n_in,
                              void* d_out, int out_size, void* d_ws, size_t ws_size,
                              hipStream_t stream) {
    const float* AB = (const float*)d_in[0];  // vol_AB
    const float* BA = (const float*)d_in[1];  // vol_BA
    const float* BC = (const float*)d_in[2];  // vol_BC
    const float* CB = (const float*)d_in[3];  // vol_CB
    const float* AC = (const float*)d_in[4];  // vol_AC
    const float* CA = (const float*)d_in[5];  // vol_CA
    // d_in[6..8] (xy/yz/xz rel ids) are unused by the reference.

    const long nElems = in_sizes[0];  // N*2
    const int block = 256;
    const int grid = 2048;            // 8 blocks/CU resident; ~8 iters/thread

    // d_out is poisoned with 0xAA before every timed launch — zero it.
    hipMemsetAsync(d_out, 0, (size_t)out_size * sizeof(float), stream);
    box_loss_kernel<<<grid, block, 0, stream>>>(AB, BA, BC, CB, AC, CA,
                                                (float*)d_out, nElems);
}